// Round 3
// baseline (313.643 us; speedup 1.0000x reference)
//
#include <hip/hip_runtime.h>
#include <stdint.h>

typedef unsigned short u16;
typedef __bf16 bf16x8 __attribute__((ext_vector_type(8)));
typedef float f32x16 __attribute__((ext_vector_type(16)));
typedef u16 u16x8 __attribute__((ext_vector_type(8)));

__device__ __forceinline__ u16 f2bf(float f) {
  uint32_t u = __float_as_uint(f);
  u += 0x7fffu + ((u >> 16) & 1u);   // round-to-nearest-even
  return (u16)(u >> 16);
}

// ---------------------------------------------------------------------------
// build_lr: blocks 0..15 build L4[A_L(128)][B_L(128)][r4(16)] (fp32, 1 MiB),
//           block 16 builds R[A_R(16)][B_R(16)][r4(16)] (fp32, 16 KiB).
// Digit order: A = a0 most significant ... a8 least. Core 7 is bond-swapped.
// ---------------------------------------------------------------------------
__global__ __launch_bounds__(256) void build_lr_kernel(
    const float* __restrict__ p0, const float* __restrict__ p1,
    const float* __restrict__ p2, const float* __restrict__ p3,
    const float* __restrict__ p4, const float* __restrict__ p5,
    const float* __restrict__ p6, const float* __restrict__ p7,
    const float* __restrict__ p8, float* __restrict__ L4, float* __restrict__ R) {
  __shared__ float sA[16384];
  __shared__ float sB[4096];
  const int tid = threadIdx.x;
  if (blockIdx.x < 16) {
    for (int i = tid; i < 1024; i += 256) sA[i] = p0[i];
    __syncthreads();
    // step1: sA[8][8][16] x p1 -> sB[16][16][16]
    for (int i = tid; i < 4096; i += 256) {
      int r = i & 15, t = i >> 4;
      int Bb = t & 15, Aa = t >> 4;
      int a = Aa & 1, A = Aa >> 1, b = Bb & 1, B = Bb >> 1;
      const float* srow = sA + (A * 8 + B) * 16;
      const float* g = p1 + ((a * 2 + b) * 16) * 16 + r;
      float s = 0.f;
#pragma unroll
      for (int l = 0; l < 16; l++) s += srow[l] * g[l * 16];
      sB[i] = s;
    }
    __syncthreads();
    // step2: sB[16][16][16] x p2 -> sA[32][32][16]
    for (int i = tid; i < 16384; i += 256) {
      int r = i & 15, t = i >> 4;
      int Bb = t & 31, Aa = t >> 5;
      int a = Aa & 1, A = Aa >> 1, b = Bb & 1, B = Bb >> 1;
      const float* srow = sB + (A * 16 + B) * 16;
      const float* g = p2 + ((a * 2 + b) * 16) * 16 + r;
      float s = 0.f;
#pragma unroll
      for (int l = 0; l < 16; l++) s += srow[l] * g[l * 16];
      sA[i] = s;
    }
    __syncthreads();
    // fused steps 3+4
    int gi = blockIdx.x * 256 + tid;  // 0..4095
    int b3 = gi & 1, a3 = (gi >> 1) & 1;
    int B2 = (gi >> 2) & 31, A2 = gi >> 7;
    const float* srow = sA + (A2 * 32 + B2) * 16;
    const float* g3 = p3 + ((a3 * 2 + b3) * 16) * 16;
    float tmp[16];
#pragma unroll
    for (int r3 = 0; r3 < 16; r3++) {
      float s = 0.f;
#pragma unroll
      for (int r2 = 0; r2 < 16; r2++) s += srow[r2] * g3[r2 * 16 + r3];
      tmp[r3] = s;
    }
#pragma unroll
    for (int ab = 0; ab < 4; ab++) {
      int a4 = ab >> 1, b4 = ab & 1;
      const float* g4 = p4 + (ab * 16) * 16;
      int AL = A2 * 4 + a3 * 2 + a4;
      int BL = B2 * 4 + b3 * 2 + b4;
      float* drow = L4 + (AL * 128 + BL) * 16;
#pragma unroll
      for (int r4 = 0; r4 < 16; r4++) {
        float s = 0.f;
#pragma unroll
        for (int r3 = 0; r3 < 16; r3++) s += tmp[r3] * g4[r3 * 16 + r4];
        drow[r4] = s;
      }
    }
  } else {
    for (int i = tid; i < 64; i += 256) sA[i] = p8[i];
    __syncthreads();
    // k=7 (bond-swapped)
    for (int i = tid; i < 256; i += 256) {
      int rl = i & 15, t = i >> 4;
      int Bt = t & 3, At = t >> 2;
      int a = At >> 1, Ap = At & 1, b = Bt >> 1, Bp = Bt & 1;
      const float* srow = sA + (Ap * 2 + Bp) * 16;
      const float* g = p7 + ((a * 2 + b) * 16) * 16 + rl;
      float s = 0.f;
#pragma unroll
      for (int rk = 0; rk < 16; rk++) s += srow[rk] * g[rk * 16];
      sB[i] = s;
    }
    __syncthreads();
    // k=6
    for (int i = tid; i < 1024; i += 256) {
      int rl = i & 15, t = i >> 4;
      int Bt = t & 7, At = t >> 3;
      int a = At >> 2, Ap = At & 3, b = Bt >> 2, Bp = Bt & 3;
      const float* srow = sB + (Ap * 4 + Bp) * 16;
      const float* g = p6 + (((a * 2 + b) * 16) + rl) * 16;
      float s = 0.f;
#pragma unroll
      for (int rk = 0; rk < 16; rk++) s += srow[rk] * g[rk];
      sA[i] = s;
    }
    __syncthreads();
    // k=5
    for (int i = tid; i < 4096; i += 256) {
      int rl = i & 15, t = i >> 4;
      int Bt = t & 15, At = t >> 4;
      int a = At >> 3, Ap = At & 7, b = Bt >> 3, Bp = Bt & 7;
      const float* srow = sA + (Ap * 8 + Bp) * 16;
      const float* g = p5 + (((a * 2 + b) * 16) + rl) * 16;
      float s = 0.f;
#pragma unroll
      for (int rk = 0; rk < 16; rk++) s += srow[rk] * g[rk];
      R[i] = s;
    }
  }
}

// ---------------------------------------------------------------------------
// merge: 8 outputs/thread along Af (same L4 row reused x8), u16x8 store.
// Wt[n][k] = sum_r L4[k>>4][n>>4][r] * R[k&15][n&15][r], bf16.
// ---------------------------------------------------------------------------
__global__ __launch_bounds__(256) void merge_kernel(const float* __restrict__ L4,
                                                    const float* __restrict__ R,
                                                    u16* __restrict__ Wt) {
  int t = blockIdx.x * 256 + threadIdx.x;   // 0 .. 2048*2048/8
  int e = t * 8;
  int Af = e & 2047;                        // k index (8-aligned)
  int Bf = e >> 11;                         // n index
  const float* lrow = L4 + ((Af >> 4) * 128 + (Bf >> 4)) * 16;
  float lv[16];
#pragma unroll
  for (int r = 0; r < 16; r++) lv[r] = lrow[r];
  const float* rbase = R + (Bf & 15) * 16;  // + (Af&15)*256
  u16x8 o;
#pragma unroll
  for (int j = 0; j < 8; j++) {
    const float* rrow = rbase + ((Af + j) & 15) * 256;
    float s = 0.f;
#pragma unroll
    for (int r = 0; r < 16; r++) s += lv[r] * rrow[r];
    o[j] = f2bf(s);
  }
  *(u16x8*)(Wt + (size_t)Bf * 2048 + Af) = o;
}

// ---------------------------------------------------------------------------
// cast_x: fp32 -> bf16, 8 elements per thread.
// ---------------------------------------------------------------------------
__global__ __launch_bounds__(256) void cast_x_kernel(const float* __restrict__ x,
                                                     u16* __restrict__ xb) {
  size_t i = ((size_t)blockIdx.x * 256 + threadIdx.x) * 8;
  float4 u = *(const float4*)(x + i);
  float4 v = *(const float4*)(x + i + 4);
  u16x8 o;
  o[0] = f2bf(u.x); o[1] = f2bf(u.y); o[2] = f2bf(u.z); o[3] = f2bf(u.w);
  o[4] = f2bf(v.x); o[5] = f2bf(v.y); o[6] = f2bf(v.z); o[7] = f2bf(v.w);
  *(u16x8*)(xb + i) = o;
}

// ---------------------------------------------------------------------------
// gemm: C[8192][2048] = A * Wt^T, bf16 in / fp32 out.
// 128x128 tile, BK=64 (32 iters), 4 waves 2x2, v_mfma_f32_32x32x16_bf16.
// LDS layout per 8-row group: [kchunk(8)][row-in-group(8)][8 u16] so that
// (a) global_load_lds (dest = base + lane*16) stages it with lane l ->
//     global row (l&7), kchunk (l>>3); and
// (b) fragment reads cover contiguous 256 B per group -> bank-conflict-free.
// A-frag: lane(r32,half) holds A[r32][k = ks*16 + half*8 + j] (round-2 verified)
// C/D   : col=lane&31, row=(reg&3)+8*(reg>>2)+4*half (m74/m101-verified)
// ---------------------------------------------------------------------------
__global__ __launch_bounds__(256) void gemm_kernel(const u16* __restrict__ A,
                                                   const u16* __restrict__ B,
                                                   float* __restrict__ C) {
  __shared__ u16 As[128 * 64];   // 16 KiB
  __shared__ u16 Bs[128 * 64];   // 16 KiB
  const int tid = threadIdx.x;
  const int lane = tid & 63;
  const int w = tid >> 6;
  const int m0 = blockIdx.y * 128;
  const int n0 = blockIdx.x * 128;
  const int wm = (w >> 1) * 64;
  const int wn = (w & 1) * 64;
  const int r32 = lane & 31;
  const int half = lane >> 5;
  const int srow = lane & 7;         // staging: row within 8-row group
  const int scol = (lane >> 3) * 8;  // staging: bf16 elem offset (16B/lane)

  // wave w stages 8-row groups {q*4+w : q=0..3} for both A and B
  const u16* gaA = A + (size_t)(m0 + w * 8 + srow) * 2048 + scol;
  const u16* gaB = B + (size_t)(n0 + w * 8 + srow) * 2048 + scol;

  f32x16 acc[2][2] = {};

  for (int k0 = 0; k0 < 2048; k0 += 64) {
#pragma unroll
    for (int q = 0; q < 4; q++) {
      __builtin_amdgcn_global_load_lds(
          (const __attribute__((address_space(1))) void*)(gaA + k0 + (size_t)q * 32 * 2048),
          (__attribute__((address_space(3))) void*)(As + (q * 4 + w) * 512), 16, 0, 0);
      __builtin_amdgcn_global_load_lds(
          (const __attribute__((address_space(1))) void*)(gaB + k0 + (size_t)q * 32 * 2048),
          (__attribute__((address_space(3))) void*)(Bs + (q * 4 + w) * 512), 16, 0, 0);
    }
    __syncthreads();
    bf16x8 af[2][4], bv[2][4];
#pragma unroll
    for (int mt = 0; mt < 2; mt++)
#pragma unroll
      for (int ks = 0; ks < 4; ks++)
        af[mt][ks] = *(const bf16x8*)(As + ((wm + mt * 32 + r32) >> 3) * 512 +
                                      (ks * 2 + half) * 64 + (r32 & 7) * 8);
#pragma unroll
    for (int nt = 0; nt < 2; nt++)
#pragma unroll
      for (int ks = 0; ks < 4; ks++)
        bv[nt][ks] = *(const bf16x8*)(Bs + ((wn + nt * 32 + r32) >> 3) * 512 +
                                      (ks * 2 + half) * 64 + (r32 & 7) * 8);
#pragma unroll
    for (int ks = 0; ks < 4; ks++)
#pragma unroll
      for (int mt = 0; mt < 2; mt++)
#pragma unroll
        for (int nt = 0; nt < 2; nt++)
          acc[mt][nt] = __builtin_amdgcn_mfma_f32_32x32x16_bf16(af[mt][ks], bv[nt][ks], acc[mt][nt], 0, 0, 0);
    __syncthreads();
  }
#pragma unroll
  for (int mt = 0; mt < 2; mt++) {
#pragma unroll
    for (int nt = 0; nt < 2; nt++) {
      size_t cbase = (size_t)(m0 + wm + mt * 32 + 4 * half) * 2048 + (n0 + wn + nt * 32 + r32);
#pragma unroll
      for (int reg = 0; reg < 16; reg++) {
        int row = (reg & 3) + 8 * (reg >> 2);   // + 4*half folded into cbase
        C[cbase + (size_t)row * 2048] = acc[mt][nt][reg];
      }
    }
  }
}

extern "C" void kernel_launch(void* const* d_in, const int* in_sizes, int n_in,
                              void* d_out, int out_size, void* d_ws, size_t ws_size,
                              hipStream_t stream) {
  const float* x = (const float*)d_in[0];
  const float* p0 = (const float*)d_in[1];
  const float* p1 = (const float*)d_in[2];
  const float* p2 = (const float*)d_in[3];
  const float* p3 = (const float*)d_in[4];
  const float* p4 = (const float*)d_in[5];
  const float* p5 = (const float*)d_in[6];
  const float* p6 = (const float*)d_in[7];
  const float* p7 = (const float*)d_in[8];
  const float* p8 = (const float*)d_in[9];
  char* ws = (char*)d_ws;
  // ws layout (bytes): xbf 33554432 | Wt 8388608 | L4 1048576 | R 16384
  u16* xbf = (u16*)ws;
  u16* Wt = (u16*)(ws + 33554432);
  float* L4 = (float*)(ws + 41943040);
  float* R = (float*)(ws + 42991616);

  build_lr_kernel<<<17, 256, 0, stream>>>(p0, p1, p2, p3, p4, p5, p6, p7, p8, L4, R);
  merge_kernel<<<2048, 256, 0, stream>>>(L4, R, Wt);
  cast_x_kernel<<<8192, 256, 0, stream>>>(x, xbf);
  gemm_kernel<<<dim3(16, 64), 256, 0, stream>>>(xbf, Wt, (float*)d_out);
}

// Round 4
// 271.079 us; speedup vs baseline: 1.1570x; 1.1570x over previous
//
#include <hip/hip_runtime.h>
#include <stdint.h>

typedef unsigned short u16;
typedef __bf16 bf16x8 __attribute__((ext_vector_type(8)));
typedef float f32x16 __attribute__((ext_vector_type(16)));
typedef u16 u16x8 __attribute__((ext_vector_type(8)));

__device__ __forceinline__ u16 f2bf(float f) {
  uint32_t u = __float_as_uint(f);
  u += 0x7fffu + ((u >> 16) & 1u);   // round-to-nearest-even
  return (u16)(u >> 16);
}

// ---------------------------------------------------------------------------
// build_lr: blocks 0..15 build L4[A_L(128)][B_L(128)][r4(16)] (fp32, 1 MiB),
//           block 16 builds R[A_R(16)][B_R(16)][r4(16)] (fp32, 16 KiB).
// Digit order: A = a0 most significant ... a8 least. Core 7 is bond-swapped.
// ---------------------------------------------------------------------------
__global__ __launch_bounds__(256) void build_lr_kernel(
    const float* __restrict__ p0, const float* __restrict__ p1,
    const float* __restrict__ p2, const float* __restrict__ p3,
    const float* __restrict__ p4, const float* __restrict__ p5,
    const float* __restrict__ p6, const float* __restrict__ p7,
    const float* __restrict__ p8, float* __restrict__ L4, float* __restrict__ R) {
  __shared__ float sA[16384];
  __shared__ float sB[4096];
  const int tid = threadIdx.x;
  if (blockIdx.x < 16) {
    for (int i = tid; i < 1024; i += 256) sA[i] = p0[i];
    __syncthreads();
    // step1: sA[8][8][16] x p1 -> sB[16][16][16]
    for (int i = tid; i < 4096; i += 256) {
      int r = i & 15, t = i >> 4;
      int Bb = t & 15, Aa = t >> 4;
      int a = Aa & 1, A = Aa >> 1, b = Bb & 1, B = Bb >> 1;
      const float* srow = sA + (A * 8 + B) * 16;
      const float* g = p1 + ((a * 2 + b) * 16) * 16 + r;
      float s = 0.f;
#pragma unroll
      for (int l = 0; l < 16; l++) s += srow[l] * g[l * 16];
      sB[i] = s;
    }
    __syncthreads();
    // step2: sB[16][16][16] x p2 -> sA[32][32][16]
    for (int i = tid; i < 16384; i += 256) {
      int r = i & 15, t = i >> 4;
      int Bb = t & 31, Aa = t >> 5;
      int a = Aa & 1, A = Aa >> 1, b = Bb & 1, B = Bb >> 1;
      const float* srow = sB + (A * 16 + B) * 16;
      const float* g = p2 + ((a * 2 + b) * 16) * 16 + r;
      float s = 0.f;
#pragma unroll
      for (int l = 0; l < 16; l++) s += srow[l] * g[l * 16];
      sA[i] = s;
    }
    __syncthreads();
    // fused steps 3+4
    int gi = blockIdx.x * 256 + tid;  // 0..4095
    int b3 = gi & 1, a3 = (gi >> 1) & 1;
    int B2 = (gi >> 2) & 31, A2 = gi >> 7;
    const float* srow = sA + (A2 * 32 + B2) * 16;
    const float* g3 = p3 + ((a3 * 2 + b3) * 16) * 16;
    float tmp[16];
#pragma unroll
    for (int r3 = 0; r3 < 16; r3++) {
      float s = 0.f;
#pragma unroll
      for (int r2 = 0; r2 < 16; r2++) s += srow[r2] * g3[r2 * 16 + r3];
      tmp[r3] = s;
    }
#pragma unroll
    for (int ab = 0; ab < 4; ab++) {
      int a4 = ab >> 1, b4 = ab & 1;
      const float* g4 = p4 + (ab * 16) * 16;
      int AL = A2 * 4 + a3 * 2 + a4;
      int BL = B2 * 4 + b3 * 2 + b4;
      float* drow = L4 + (AL * 128 + BL) * 16;
#pragma unroll
      for (int r4 = 0; r4 < 16; r4++) {
        float s = 0.f;
#pragma unroll
        for (int r3 = 0; r3 < 16; r3++) s += tmp[r3] * g4[r3 * 16 + r4];
        drow[r4] = s;
      }
    }
  } else {
    for (int i = tid; i < 64; i += 256) sA[i] = p8[i];
    __syncthreads();
    // k=7 (bond-swapped)
    for (int i = tid; i < 256; i += 256) {
      int rl = i & 15, t = i >> 4;
      int Bt = t & 3, At = t >> 2;
      int a = At >> 1, Ap = At & 1, b = Bt >> 1, Bp = Bt & 1;
      const float* srow = sA + (Ap * 2 + Bp) * 16;
      const float* g = p7 + ((a * 2 + b) * 16) * 16 + rl;
      float s = 0.f;
#pragma unroll
      for (int rk = 0; rk < 16; rk++) s += srow[rk] * g[rk * 16];
      sB[i] = s;
    }
    __syncthreads();
    // k=6
    for (int i = tid; i < 1024; i += 256) {
      int rl = i & 15, t = i >> 4;
      int Bt = t & 7, At = t >> 3;
      int a = At >> 2, Ap = At & 3, b = Bt >> 2, Bp = Bt & 3;
      const float* srow = sB + (Ap * 4 + Bp) * 16;
      const float* g = p6 + (((a * 2 + b) * 16) + rl) * 16;
      float s = 0.f;
#pragma unroll
      for (int rk = 0; rk < 16; rk++) s += srow[rk] * g[rk];
      sA[i] = s;
    }
    __syncthreads();
    // k=5
    for (int i = tid; i < 4096; i += 256) {
      int rl = i & 15, t = i >> 4;
      int Bt = t & 15, At = t >> 4;
      int a = At >> 3, Ap = At & 7, b = Bt >> 3, Bp = Bt & 7;
      const float* srow = sA + (Ap * 8 + Bp) * 16;
      const float* g = p5 + (((a * 2 + b) * 16) + rl) * 16;
      float s = 0.f;
#pragma unroll
      for (int rk = 0; rk < 16; rk++) s += srow[rk] * g[rk];
      R[i] = s;
    }
  }
}

// ---------------------------------------------------------------------------
// merge: 8 outputs/thread along Af (same L4 row reused x8), u16x8 store.
// Wt[n][k] = sum_r L4[k>>4][n>>4][r] * R[k&15][n&15][r], bf16.
// ---------------------------------------------------------------------------
__global__ __launch_bounds__(256) void merge_kernel(const float* __restrict__ L4,
                                                    const float* __restrict__ R,
                                                    u16* __restrict__ Wt) {
  int t = blockIdx.x * 256 + threadIdx.x;   // 0 .. 2048*2048/8
  int e = t * 8;
  int Af = e & 2047;                        // k index (8-aligned)
  int Bf = e >> 11;                         // n index
  const float* lrow = L4 + ((Af >> 4) * 128 + (Bf >> 4)) * 16;
  float lv[16];
#pragma unroll
  for (int r = 0; r < 16; r++) lv[r] = lrow[r];
  const float* rbase = R + (Bf & 15) * 16;  // + (Af&15)*256
  u16x8 o;
#pragma unroll
  for (int j = 0; j < 8; j++) {
    const float* rrow = rbase + ((Af + j) & 15) * 256;
    float s = 0.f;
#pragma unroll
    for (int r = 0; r < 16; r++) s += lv[r] * rrow[r];
    o[j] = f2bf(s);
  }
  *(u16x8*)(Wt + (size_t)Bf * 2048 + Af) = o;
}

// ---------------------------------------------------------------------------
// cast_x: fp32 -> bf16, 8 elements per thread.
// ---------------------------------------------------------------------------
__global__ __launch_bounds__(256) void cast_x_kernel(const float* __restrict__ x,
                                                     u16* __restrict__ xb) {
  size_t i = ((size_t)blockIdx.x * 256 + threadIdx.x) * 8;
  float4 u = *(const float4*)(x + i);
  float4 v = *(const float4*)(x + i + 4);
  u16x8 o;
  o[0] = f2bf(u.x); o[1] = f2bf(u.y); o[2] = f2bf(u.z); o[3] = f2bf(u.w);
  o[4] = f2bf(v.x); o[5] = f2bf(v.y); o[6] = f2bf(v.z); o[7] = f2bf(v.w);
  *(u16x8*)(xb + i) = o;
}

// ---------------------------------------------------------------------------
// gemm: C[8192][2048] = A * Wt^T, bf16 in / fp32 out.
// R2 structure (BK=32, 128x128 tile, 4 waves 2x2, v_mfma_f32_32x32x16_bf16,
// quad-coalesced global_load_lds staging) + XOR-swizzled LDS layout:
// row R's k-octet o (16 B) is stored at position p = o ^ ((R>>1)&3) within
// R's 64 B row. Staging lane (lrow=lane>>2, p=lane&3) therefore fetches
// global octet o = p ^ ((lrow>>1)&3) -- each quad still covers one full
// 64 B line (permuted within the line), so global coalescing is unchanged.
// Fragment reads: addr%128 = (r32&1)*64 + ((o^(r32>>1)&3))*16 -> every
// consecutive-8-lane group tiles the 128 B bank space exactly (conflict floor).
// A-frag: lane(r32,half) holds A[r32][k=ks*16+half*8+j] (round-2 verified)
// C/D   : col=lane&31, row=(reg&3)+8*(reg>>2)+4*half (m74/m101-verified)
// ---------------------------------------------------------------------------
__global__ __launch_bounds__(256) void gemm_kernel(const u16* __restrict__ A,
                                                   const u16* __restrict__ B,
                                                   float* __restrict__ C) {
  __shared__ u16 As[128 * 32];
  __shared__ u16 Bs[128 * 32];
  const int tid = threadIdx.x;
  const int lane = tid & 63;
  const int w = tid >> 6;
  const int m0 = blockIdx.y * 128;
  const int n0 = blockIdx.x * 128;
  const int wm = (w >> 1) * 64;
  const int wn = (w & 1) * 64;
  const int r32 = lane & 31;
  const int half = lane >> 5;
  const int lrow = lane >> 2;                      // staging row within group
  const int oct = (lane & 3) ^ ((lrow >> 1) & 3);  // global octet this lane fetches

  const u16* ga0 = A + (size_t)(m0 + w * 16 + lrow) * 2048 + oct * 8;
  const u16* gb0 = B + (size_t)(n0 + w * 16 + lrow) * 2048 + oct * 8;

  const int sw = (r32 >> 1) & 3;   // read-side swizzle key for row r32

  f32x16 acc[2][2] = {};

  for (int k0 = 0; k0 < 2048; k0 += 32) {
#pragma unroll
    for (int rr = 0; rr < 2; rr++) {
      __builtin_amdgcn_global_load_lds(
          (const __attribute__((address_space(1))) void*)(ga0 + k0 + (size_t)rr * 64 * 2048),
          (__attribute__((address_space(3))) void*)(As + (rr * 64 + w * 16) * 32), 16, 0, 0);
      __builtin_amdgcn_global_load_lds(
          (const __attribute__((address_space(1))) void*)(gb0 + k0 + (size_t)rr * 64 * 2048),
          (__attribute__((address_space(3))) void*)(Bs + (rr * 64 + w * 16) * 32), 16, 0, 0);
    }
    __syncthreads();
    bf16x8 af[2][2], bv[2][2];
#pragma unroll
    for (int mt = 0; mt < 2; mt++)
#pragma unroll
      for (int ks = 0; ks < 2; ks++)
        af[mt][ks] = *(const bf16x8*)(As + (wm + mt * 32 + r32) * 32 +
                                      ((ks * 2 + half) ^ sw) * 8);
#pragma unroll
    for (int nt = 0; nt < 2; nt++)
#pragma unroll
      for (int ks = 0; ks < 2; ks++)
        bv[nt][ks] = *(const bf16x8*)(Bs + (wn + nt * 32 + r32) * 32 +
                                      ((ks * 2 + half) ^ sw) * 8);
#pragma unroll
    for (int ks = 0; ks < 2; ks++)
#pragma unroll
      for (int mt = 0; mt < 2; mt++)
#pragma unroll
        for (int nt = 0; nt < 2; nt++)
          acc[mt][nt] = __builtin_amdgcn_mfma_f32_32x32x16_bf16(af[mt][ks], bv[nt][ks], acc[mt][nt], 0, 0, 0);
    __syncthreads();
  }
#pragma unroll
  for (int mt = 0; mt < 2; mt++) {
#pragma unroll
    for (int nt = 0; nt < 2; nt++) {
      size_t cbase = (size_t)(m0 + wm + mt * 32 + 4 * half) * 2048 + (n0 + wn + nt * 32 + r32);
#pragma unroll
      for (int reg = 0; reg < 16; reg++) {
        int row = (reg & 3) + 8 * (reg >> 2);   // + 4*half folded into cbase
        C[cbase + (size_t)row * 2048] = acc[mt][nt][reg];
      }
    }
  }
}

extern "C" void kernel_launch(void* const* d_in, const int* in_sizes, int n_in,
                              void* d_out, int out_size, void* d_ws, size_t ws_size,
                              hipStream_t stream) {
  const float* x = (const float*)d_in[0];
  const float* p0 = (const float*)d_in[1];
  const float* p1 = (const float*)d_in[2];
  const float* p2 = (const float*)d_in[3];
  const float* p3 = (const float*)d_in[4];
  const float* p4 = (const float*)d_in[5];
  const float* p5 = (const float*)d_in[6];
  const float* p6 = (const float*)d_in[7];
  const float* p7 = (const float*)d_in[8];
  const float* p8 = (const float*)d_in[9];
  char* ws = (char*)d_ws;
  // ws layout (bytes): xbf 33554432 | Wt 8388608 | L4 1048576 | R 16384
  u16* xbf = (u16*)ws;
  u16* Wt = (u16*)(ws + 33554432);
  float* L4 = (float*)(ws + 41943040);
  float* R = (float*)(ws + 42991616);

  build_lr_kernel<<<17, 256, 0, stream>>>(p0, p1, p2, p3, p4, p5, p6, p7, p8, L4, R);
  merge_kernel<<<2048, 256, 0, stream>>>(L4, R, Wt);
  cast_x_kernel<<<8192, 256, 0, stream>>>(x, xbf);
  gemm_kernel<<<dim3(16, 64), 256, 0, stream>>>(xbf, Wt, (float*)d_out);
}

// Round 5
// 269.878 us; speedup vs baseline: 1.1622x; 1.0044x over previous
//
#include <hip/hip_runtime.h>
#include <stdint.h>

typedef unsigned short u16;
typedef __bf16 bf16x8 __attribute__((ext_vector_type(8)));
typedef float f32x16 __attribute__((ext_vector_type(16)));
typedef u16 u16x8 __attribute__((ext_vector_type(8)));

__device__ __forceinline__ u16 f2bf(float f) {
  uint32_t u = __float_as_uint(f);
  u += 0x7fffu + ((u >> 16) & 1u);   // round-to-nearest-even
  return (u16)(u >> 16);
}

// ---------------------------------------------------------------------------
// build_lr: blocks 0..15 build L4[A_L(128)][B_L(128)][r4(16)] (fp32, 1 MiB),
//           block 16 builds R[A_R(16)][B_R(16)][r4(16)] (fp32, 16 KiB).
// Digit order: A = a0 most significant ... a8 least. Core 7 is bond-swapped.
// ---------------------------------------------------------------------------
__global__ __launch_bounds__(256) void build_lr_kernel(
    const float* __restrict__ p0, const float* __restrict__ p1,
    const float* __restrict__ p2, const float* __restrict__ p3,
    const float* __restrict__ p4, const float* __restrict__ p5,
    const float* __restrict__ p6, const float* __restrict__ p7,
    const float* __restrict__ p8, float* __restrict__ L4, float* __restrict__ R) {
  __shared__ float sA[16384];
  __shared__ float sB[4096];
  const int tid = threadIdx.x;
  if (blockIdx.x < 16) {
    for (int i = tid; i < 1024; i += 256) sA[i] = p0[i];
    __syncthreads();
    // step1: sA[8][8][16] x p1 -> sB[16][16][16]
    for (int i = tid; i < 4096; i += 256) {
      int r = i & 15, t = i >> 4;
      int Bb = t & 15, Aa = t >> 4;
      int a = Aa & 1, A = Aa >> 1, b = Bb & 1, B = Bb >> 1;
      const float* srow = sA + (A * 8 + B) * 16;
      const float* g = p1 + ((a * 2 + b) * 16) * 16 + r;
      float s = 0.f;
#pragma unroll
      for (int l = 0; l < 16; l++) s += srow[l] * g[l * 16];
      sB[i] = s;
    }
    __syncthreads();
    // step2: sB[16][16][16] x p2 -> sA[32][32][16]
    for (int i = tid; i < 16384; i += 256) {
      int r = i & 15, t = i >> 4;
      int Bb = t & 31, Aa = t >> 5;
      int a = Aa & 1, A = Aa >> 1, b = Bb & 1, B = Bb >> 1;
      const float* srow = sB + (A * 16 + B) * 16;
      const float* g = p2 + ((a * 2 + b) * 16) * 16 + r;
      float s = 0.f;
#pragma unroll
      for (int l = 0; l < 16; l++) s += srow[l] * g[l * 16];
      sA[i] = s;
    }
    __syncthreads();
    // fused steps 3+4
    int gi = blockIdx.x * 256 + tid;  // 0..4095
    int b3 = gi & 1, a3 = (gi >> 1) & 1;
    int B2 = (gi >> 2) & 31, A2 = gi >> 7;
    const float* srow = sA + (A2 * 32 + B2) * 16;
    const float* g3 = p3 + ((a3 * 2 + b3) * 16) * 16;
    float tmp[16];
#pragma unroll
    for (int r3 = 0; r3 < 16; r3++) {
      float s = 0.f;
#pragma unroll
      for (int r2 = 0; r2 < 16; r2++) s += srow[r2] * g3[r2 * 16 + r3];
      tmp[r3] = s;
    }
#pragma unroll
    for (int ab = 0; ab < 4; ab++) {
      int a4 = ab >> 1, b4 = ab & 1;
      const float* g4 = p4 + (ab * 16) * 16;
      int AL = A2 * 4 + a3 * 2 + a4;
      int BL = B2 * 4 + b3 * 2 + b4;
      float* drow = L4 + (AL * 128 + BL) * 16;
#pragma unroll
      for (int r4 = 0; r4 < 16; r4++) {
        float s = 0.f;
#pragma unroll
        for (int r3 = 0; r3 < 16; r3++) s += tmp[r3] * g4[r3 * 16 + r4];
        drow[r4] = s;
      }
    }
  } else {
    for (int i = tid; i < 64; i += 256) sA[i] = p8[i];
    __syncthreads();
    // k=7 (bond-swapped)
    for (int i = tid; i < 256; i += 256) {
      int rl = i & 15, t = i >> 4;
      int Bt = t & 3, At = t >> 2;
      int a = At >> 1, Ap = At & 1, b = Bt >> 1, Bp = Bt & 1;
      const float* srow = sA + (Ap * 2 + Bp) * 16;
      const float* g = p7 + ((a * 2 + b) * 16) * 16 + rl;
      float s = 0.f;
#pragma unroll
      for (int rk = 0; rk < 16; rk++) s += srow[rk] * g[rk * 16];
      sB[i] = s;
    }
    __syncthreads();
    // k=6
    for (int i = tid; i < 1024; i += 256) {
      int rl = i & 15, t = i >> 4;
      int Bt = t & 7, At = t >> 3;
      int a = At >> 2, Ap = At & 3, b = Bt >> 2, Bp = Bt & 3;
      const float* srow = sB + (Ap * 4 + Bp) * 16;
      const float* g = p6 + (((a * 2 + b) * 16) + rl) * 16;
      float s = 0.f;
#pragma unroll
      for (int rk = 0; rk < 16; rk++) s += srow[rk] * g[rk];
      sA[i] = s;
    }
    __syncthreads();
    // k=5
    for (int i = tid; i < 4096; i += 256) {
      int rl = i & 15, t = i >> 4;
      int Bt = t & 15, At = t >> 4;
      int a = At >> 3, Ap = At & 7, b = Bt >> 3, Bp = Bt & 7;
      const float* srow = sA + (Ap * 8 + Bp) * 16;
      const float* g = p5 + (((a * 2 + b) * 16) + rl) * 16;
      float s = 0.f;
#pragma unroll
      for (int rk = 0; rk < 16; rk++) s += srow[rk] * g[rk];
      R[i] = s;
    }
  }
}

// ---------------------------------------------------------------------------
// merge: 8 outputs/thread along Af (same L4 row reused x8), u16x8 store.
// Wt[n][k] = sum_r L4[k>>4][n>>4][r] * R[k&15][n&15][r], bf16.
// ---------------------------------------------------------------------------
__global__ __launch_bounds__(256) void merge_kernel(const float* __restrict__ L4,
                                                    const float* __restrict__ R,
                                                    u16* __restrict__ Wt) {
  int t = blockIdx.x * 256 + threadIdx.x;   // 0 .. 2048*2048/8
  int e = t * 8;
  int Af = e & 2047;                        // k index (8-aligned)
  int Bf = e >> 11;                         // n index
  const float* lrow = L4 + ((Af >> 4) * 128 + (Bf >> 4)) * 16;
  float lv[16];
#pragma unroll
  for (int r = 0; r < 16; r++) lv[r] = lrow[r];
  const float* rbase = R + (Bf & 15) * 16;  // + (Af&15)*256
  u16x8 o;
#pragma unroll
  for (int j = 0; j < 8; j++) {
    const float* rrow = rbase + ((Af + j) & 15) * 256;
    float s = 0.f;
#pragma unroll
    for (int r = 0; r < 16; r++) s += lv[r] * rrow[r];
    o[j] = f2bf(s);
  }
  *(u16x8*)(Wt + (size_t)Bf * 2048 + Af) = o;
}

// ---------------------------------------------------------------------------
// cast_x: fp32 -> bf16, 8 elements per thread.
// ---------------------------------------------------------------------------
__global__ __launch_bounds__(256) void cast_x_kernel(const float* __restrict__ x,
                                                     u16* __restrict__ xb) {
  size_t i = ((size_t)blockIdx.x * 256 + threadIdx.x) * 8;
  float4 u = *(const float4*)(x + i);
  float4 v = *(const float4*)(x + i + 4);
  u16x8 o;
  o[0] = f2bf(u.x); o[1] = f2bf(u.y); o[2] = f2bf(u.z); o[3] = f2bf(u.w);
  o[4] = f2bf(v.x); o[5] = f2bf(v.y); o[6] = f2bf(v.z); o[7] = f2bf(v.w);
  *(u16x8*)(xb + i) = o;
}

// ---------------------------------------------------------------------------
// gemm: C[8192][2048] = A * Wt^T, bf16 in / fp32 out.
// 256x128 block tile, BK=32, 4 waves stacked along m; each wave a 64x128
// tile = 2x4 of v_mfma_f32_32x32x16_bf16 -> LDS reads/MFMA = 0.75 (was 1.0).
// XOR-swizzled LDS rows (R4-verified): row R's k-octet o stored at
// p = o ^ ((R>>1)&3) within R's 64 B row; staging lane (lrow=lane>>2,
// p=lane&3) fetches global octet o = p ^ ((lrow>>1)&3) -> quad-coalesced
// global + conflict-floor LDS reads. Key uses only row bits 1-2, so r32
// suffices on the read side.
// A-frag: lane(r32,half) holds A[r32][k=ks*16+half*8+j] (R2-verified)
// C/D   : col=lane&31, row=(reg&3)+8*(reg>>2)+4*half (m74/m101-verified)
// C stores nontemporal: C is write-once; keep LLC for A-tile re-reads.
// ---------------------------------------------------------------------------
__global__ __launch_bounds__(256, 2) void gemm_kernel(const u16* __restrict__ A,
                                                      const u16* __restrict__ B,
                                                      float* __restrict__ C) {
  __shared__ u16 As[256 * 32];   // 16 KiB
  __shared__ u16 Bs[128 * 32];   // 8 KiB
  const int tid = threadIdx.x;
  const int lane = tid & 63;
  const int w = tid >> 6;
  const int m0 = blockIdx.y * 256;
  const int n0 = blockIdx.x * 128;
  const int wm = w * 64;
  const int r32 = lane & 31;
  const int half = lane >> 5;
  const int lrow = lane >> 2;                      // staging row within 16-row group
  const int oct = (lane & 3) ^ ((lrow >> 1) & 3);  // global octet this lane fetches

  // wave w stages A 16-row groups {q*4+w : q=0..3} and B groups {q*4+w : q=0..1}
  const u16* gaA = A + (size_t)(m0 + w * 16 + lrow) * 2048 + oct * 8;
  const u16* gaB = B + (size_t)(n0 + w * 16 + lrow) * 2048 + oct * 8;

  const int sw = (r32 >> 1) & 3;   // read-side swizzle key for row r32

  f32x16 acc[2][4] = {};

  for (int k0 = 0; k0 < 2048; k0 += 32) {
#pragma unroll
    for (int q = 0; q < 4; q++)
      __builtin_amdgcn_global_load_lds(
          (const __attribute__((address_space(1))) void*)(gaA + k0 + (size_t)q * 64 * 2048),
          (__attribute__((address_space(3))) void*)(As + (q * 4 + w) * 512), 16, 0, 0);
#pragma unroll
    for (int q = 0; q < 2; q++)
      __builtin_amdgcn_global_load_lds(
          (const __attribute__((address_space(1))) void*)(gaB + k0 + (size_t)q * 64 * 2048),
          (__attribute__((address_space(3))) void*)(Bs + (q * 4 + w) * 512), 16, 0, 0);
    __syncthreads();
    bf16x8 af[2][2], bv[4][2];
#pragma unroll
    for (int mt = 0; mt < 2; mt++)
#pragma unroll
      for (int ks = 0; ks < 2; ks++)
        af[mt][ks] = *(const bf16x8*)(As + (wm + mt * 32 + r32) * 32 +
                                      ((ks * 2 + half) ^ sw) * 8);
#pragma unroll
    for (int nt = 0; nt < 4; nt++)
#pragma unroll
      for (int ks = 0; ks < 2; ks++)
        bv[nt][ks] = *(const bf16x8*)(Bs + (nt * 32 + r32) * 32 +
                                      ((ks * 2 + half) ^ sw) * 8);
#pragma unroll
    for (int ks = 0; ks < 2; ks++)
#pragma unroll
      for (int mt = 0; mt < 2; mt++)
#pragma unroll
        for (int nt = 0; nt < 4; nt++)
          acc[mt][nt] = __builtin_amdgcn_mfma_f32_32x32x16_bf16(af[mt][ks], bv[nt][ks], acc[mt][nt], 0, 0, 0);
    __syncthreads();
  }
#pragma unroll
  for (int mt = 0; mt < 2; mt++) {
#pragma unroll
    for (int nt = 0; nt < 4; nt++) {
      size_t cbase = (size_t)(m0 + wm + mt * 32 + 4 * half) * 2048 + (n0 + nt * 32 + r32);
#pragma unroll
      for (int reg = 0; reg < 16; reg++) {
        int row = (reg & 3) + 8 * (reg >> 2);   // + 4*half folded into cbase
        __builtin_nontemporal_store(acc[mt][nt][reg], C + cbase + (size_t)row * 2048);
      }
    }
  }
}

extern "C" void kernel_launch(void* const* d_in, const int* in_sizes, int n_in,
                              void* d_out, int out_size, void* d_ws, size_t ws_size,
                              hipStream_t stream) {
  const float* x = (const float*)d_in[0];
  const float* p0 = (const float*)d_in[1];
  const float* p1 = (const float*)d_in[2];
  const float* p2 = (const float*)d_in[3];
  const float* p3 = (const float*)d_in[4];
  const float* p4 = (const float*)d_in[5];
  const float* p5 = (const float*)d_in[6];
  const float* p6 = (const float*)d_in[7];
  const float* p7 = (const float*)d_in[8];
  const float* p8 = (const float*)d_in[9];
  char* ws = (char*)d_ws;
  // ws layout (bytes): xbf 33554432 | Wt 8388608 | L4 1048576 | R 16384
  u16* xbf = (u16*)ws;
  u16* Wt = (u16*)(ws + 33554432);
  float* L4 = (float*)(ws + 41943040);
  float* R = (float*)(ws + 42991616);

  build_lr_kernel<<<17, 256, 0, stream>>>(p0, p1, p2, p3, p4, p5, p6, p7, p8, L4, R);
  merge_kernel<<<2048, 256, 0, stream>>>(L4, R, Wt);
  cast_x_kernel<<<8192, 256, 0, stream>>>(x, xbf);
  gemm_kernel<<<dim3(16, 32), 256, 0, stream>>>(xbf, Wt, (float*)d_out);
}